// Round 1
// baseline (803.086 us; speedup 1.0000x reference)
//
#include <hip/hip_runtime.h>
#include <hip/hip_bf16.h>

#define T_TOK 16384
#define H_DIM 1024
#define FF_DIM 4096
#define NE 8
#define CAP 2048
#define EPS_F 1e-5f

#define BM 128
#define BN 128
#define BK 32

typedef __attribute__((ext_vector_type(4))) float f32x4;
typedef __attribute__((ext_vector_type(8))) short bf16x8;
typedef unsigned long long u64;
typedef unsigned int u32;

__device__ inline void gload_lds16(const void* g, void* l) {
  __builtin_amdgcn_global_load_lds(
      (const __attribute__((address_space(1))) unsigned int*)g,
      (__attribute__((address_space(3))) unsigned int*)l, 16, 0, 0);
}

__device__ inline unsigned short bf16_bits(float f) {
  __hip_bfloat16 h = __float2bfloat16(f);
  unsigned short u;
  __builtin_memcpy(&u, &h, 2);
  return u;
}

// ---------------- router: RMSNorm + logits + softmax + composite keys ----------------
__global__ __launch_bounds__(256) void router_kernel(
    const float* __restrict__ x, const float* __restrict__ nw,
    const float* __restrict__ rw, const float* __restrict__ rb,
    __hip_bfloat16* __restrict__ xn, u64* __restrict__ keys) {
  const int t = blockIdx.x;
  const int tid = threadIdx.x;
  const float4 v = reinterpret_cast<const float4*>(x + (size_t)t * H_DIM)[tid];
  float ss = v.x * v.x + v.y * v.y + v.z * v.z + v.w * v.w;
#pragma unroll
  for (int o = 32; o > 0; o >>= 1) ss += __shfl_down(ss, o);
  __shared__ float red[4];
  __shared__ float redl[4][NE];
  const int wv = tid >> 6, ln = tid & 63;
  if (ln == 0) red[wv] = ss;
  __syncthreads();
  const float tot = red[0] + red[1] + red[2] + red[3];
  const float scale = rsqrtf(tot * (1.0f / H_DIM) + EPS_F);
  const float4 w4 = reinterpret_cast<const float4*>(nw)[tid];
  float xv0 = v.x * scale * w4.x, xv1 = v.y * scale * w4.y;
  float xv2 = v.z * scale * w4.z, xv3 = v.w * scale * w4.w;
  ushort4 u4;
  u4.x = bf16_bits(xv0); u4.y = bf16_bits(xv1);
  u4.z = bf16_bits(xv2); u4.w = bf16_bits(xv3);
  reinterpret_cast<ushort4*>(xn + (size_t)t * H_DIM)[tid] = u4;
  float lg[NE];
#pragma unroll
  for (int e = 0; e < NE; ++e) {
    const float4 r4 = reinterpret_cast<const float4*>(rw + (size_t)e * H_DIM)[tid];
    lg[e] = xv0 * r4.x + xv1 * r4.y + xv2 * r4.z + xv3 * r4.w;
  }
#pragma unroll
  for (int o = 32; o > 0; o >>= 1) {
#pragma unroll
    for (int e = 0; e < NE; ++e) lg[e] += __shfl_down(lg[e], o);
  }
  if (ln == 0) {
#pragma unroll
    for (int e = 0; e < NE; ++e) redl[wv][e] = lg[e];
  }
  __syncthreads();
  if (tid == 0) {
    float l[NE];
    float m = -1e30f;
#pragma unroll
    for (int e = 0; e < NE; ++e) {
      l[e] = redl[0][e] + redl[1][e] + redl[2][e] + redl[3][e] + rb[e];
      m = fmaxf(m, l[e]);
    }
    float s = 0.f;
#pragma unroll
    for (int e = 0; e < NE; ++e) { l[e] = expf(l[e] - m); s += l[e]; }
    const float inv = 1.0f / s;
#pragma unroll
    for (int e = 0; e < NE; ++e) {
      const float p = l[e] * inv;
      const u64 key = ((u64)__float_as_uint(p) << 32) | (u32)(0xFFFFFFFFu - (u32)t);
      keys[(size_t)e * T_TOK + t] = key;
    }
  }
}

// ---------------- per-expert radix select (exact, distinct 64-bit keys) ----------------
__global__ __launch_bounds__(256) void topk_kernel(
    const u64* __restrict__ keys, int* __restrict__ idxl,
    float* __restrict__ gatel, float* __restrict__ gsum) {
  const int e = blockIdx.x;
  const int tid = threadIdx.x;
  const u64* ke = keys + (size_t)e * T_TOK;
  __shared__ int hist[256];
  __shared__ u64 s_pref;
  __shared__ int s_k;
  __shared__ int s_cnt;
  u64 pref = 0;
  int pbits = 0;
  int kneed = CAP;
  for (int pass = 0; pass < 8; ++pass) {
    hist[tid] = 0;
    __syncthreads();
    const int shift = 56 - 8 * pass;
    for (int i = tid; i < T_TOK; i += 256) {
      const u64 key = ke[i];
      const bool ok = (pbits == 0) || ((key >> (64 - pbits)) == pref);
      if (ok) atomicAdd(&hist[(int)((key >> shift) & 255)], 1);
    }
    __syncthreads();
    if (tid == 0) {
      int cum = 0;
      int d = 255;
      for (; d >= 0; --d) {
        cum += hist[d];
        if (cum >= kneed) break;
      }
      s_k = kneed - (cum - hist[d]);
      s_pref = (pref << 8) | (u64)(u32)d;
    }
    __syncthreads();
    pref = s_pref;
    kneed = s_k;
    pbits += 8;
    __syncthreads();
  }
  if (tid == 0) s_cnt = 0;
  __syncthreads();
  for (int i = tid; i < T_TOK; i += 256) {
    const u64 key = ke[i];
    if (key >= pref) {
      const int pos = atomicAdd(&s_cnt, 1);
      if (pos < CAP) {
        const int tok = (int)(0xFFFFFFFFu - (u32)(key & 0xFFFFFFFFu));
        const float p = __uint_as_float((u32)(key >> 32));
        idxl[e * CAP + pos] = tok;
        gatel[e * CAP + pos] = p;
        atomicAdd(gsum + tok, p);
      }
    }
  }
}

// ---------------- fp32 -> bf16 weight conversion ----------------
__global__ __launch_bounds__(256) void cvt_kernel(const float* __restrict__ src,
                                                  __hip_bfloat16* __restrict__ dst, int n4) {
  int i = blockIdx.x * blockDim.x + threadIdx.x;
  const int stride = gridDim.x * blockDim.x;
  for (; i < n4; i += stride) {
    const float4 v = reinterpret_cast<const float4*>(src)[i];
    ushort4 o;
    o.x = bf16_bits(v.x); o.y = bf16_bits(v.y);
    o.z = bf16_bits(v.z); o.w = bf16_bits(v.w);
    reinterpret_cast<ushort4*>(dst)[i] = o;
  }
}

// ---------------- MFMA GEMM, m97 structure, 128x128 tile, BK=32 ----------------
// MODE 0: fc1  C[cap,FF] = gather(xn, idx) @ w1^T  -> bias+gelu -> hmid (bf16)
// MODE 1: fc2  C[cap,H]  = hmid @ w2^T             -> bias, atomic gated scatter to out
template <int MODE>
__global__ __launch_bounds__(256) void gemm_kernel(
    const __hip_bfloat16* __restrict__ Asrc, const __hip_bfloat16* __restrict__ Bw,
    const float* __restrict__ bias, const int* __restrict__ idxl,
    const float* __restrict__ gatel, __hip_bfloat16* __restrict__ hmid,
    float* __restrict__ out, int ebase) {
  constexpr int N = (MODE == 0) ? FF_DIM : H_DIM;
  constexpr int K = (MODE == 0) ? H_DIM : FF_DIM;
  const int z = blockIdx.z;
  const int e = ebase + z;
  const int bn = blockIdx.x, bm = blockIdx.y;
  const int tid = threadIdx.x;
  const int lane = tid & 63;
  const int wv = tid >> 6;
  const int wr = wv >> 1, wc = wv & 1;

  __shared__ char smem[(BM + BN) * BK * 2];  // 8KB A + 8KB B

  // staging: thread covers rows r0 and r0+64, 16B granule g; XOR-swizzle source granule
  const int r0 = tid >> 2;
  const int g = tid & 3;
  const int gsw = (g ^ ((r0 >> 1) & 3)) * 8;  // element offset of pre-swizzled granule

  const __hip_bfloat16* arow0;
  const __hip_bfloat16* arow1;
  if constexpr (MODE == 0) {
    const int t0 = idxl[e * CAP + bm * BM + r0];
    const int t1 = idxl[e * CAP + bm * BM + r0 + 64];
    arow0 = Asrc + (size_t)t0 * H_DIM + gsw;
    arow1 = Asrc + (size_t)t1 * H_DIM + gsw;
  } else {
    arow0 = Asrc + ((size_t)z * CAP + bm * BM + r0) * FF_DIM + gsw;
    arow1 = arow0 + (size_t)64 * FF_DIM;
  }
  const __hip_bfloat16* brow0 = Bw + (size_t)z * N * K + (size_t)(bn * BN + r0) * K + gsw;
  const __hip_bfloat16* brow1 = brow0 + (size_t)64 * K;

  char* ldsA0 = smem + tid * 16;
  char* ldsA1 = smem + 4096 + tid * 16;
  char* ldsB0 = smem + 8192 + tid * 16;
  char* ldsB1 = smem + 12288 + tid * 16;

  // fragment reads: row fr within 16-row fragment, k-group q; same XOR on read side
  const int fr = lane & 15, q = lane >> 4;
  const int slot = ((q ^ ((fr >> 1) & 3)) << 4);
  int offA[4], offB[4];
#pragma unroll
  for (int m = 0; m < 4; ++m) offA[m] = (wr * 64 + m * 16 + fr) * 64 + slot;
#pragma unroll
  for (int n = 0; n < 4; ++n) offB[n] = 8192 + (wc * 64 + n * 16 + fr) * 64 + slot;

  f32x4 acc[4][4] = {};

  for (int k0 = 0; k0 < K; k0 += BK) {
    __syncthreads();
    gload_lds16(arow0 + k0, ldsA0);
    gload_lds16(arow1 + k0, ldsA1);
    gload_lds16(brow0 + k0, ldsB0);
    gload_lds16(brow1 + k0, ldsB1);
    __syncthreads();
    bf16x8 af[4], bfr[4];
#pragma unroll
    for (int m = 0; m < 4; ++m) af[m] = *reinterpret_cast<const bf16x8*>(smem + offA[m]);
#pragma unroll
    for (int n = 0; n < 4; ++n) bfr[n] = *reinterpret_cast<const bf16x8*>(smem + offB[n]);
#pragma unroll
    for (int m = 0; m < 4; ++m) {
#pragma unroll
      for (int n = 0; n < 4; ++n)
        acc[m][n] = __builtin_amdgcn_mfma_f32_16x16x32_bf16(af[m], bfr[n], acc[m][n], 0, 0, 0);
    }
  }

  if constexpr (MODE == 0) {
#pragma unroll
    for (int m = 0; m < 4; ++m) {
      const int gmb = bm * BM + wr * 64 + m * 16 + q * 4;
#pragma unroll
      for (int n = 0; n < 4; ++n) {
        const int gn = bn * BN + wc * 64 + n * 16 + fr;
        const float b = bias[e * FF_DIM + gn];
#pragma unroll
        for (int i = 0; i < 4; ++i) {
          float vv = acc[m][n][i] + b;
          vv = 0.5f * vv * (1.0f + erff(vv * 0.70710678118654752f));
          hmid[((size_t)z * CAP + gmb + i) * FF_DIM + gn] = __float2bfloat16(vv);
        }
      }
    }
  } else {
#pragma unroll
    for (int m = 0; m < 4; ++m) {
      const int gmb = bm * BM + wr * 64 + m * 16 + q * 4;
      int tok[4];
      float gt[4];
#pragma unroll
      for (int i = 0; i < 4; ++i) {
        tok[i] = idxl[e * CAP + gmb + i];
        gt[i] = gatel[e * CAP + gmb + i];
      }
#pragma unroll
      for (int n = 0; n < 4; ++n) {
        const int gn = bn * BN + wc * 64 + n * 16 + fr;
        const float b = bias[e * H_DIM + gn];
#pragma unroll
        for (int i = 0; i < 4; ++i) {
          const float vv = (acc[m][n][i] + b) * gt[i];
          atomicAdd(out + (size_t)tok[i] * H_DIM + gn, vv);
        }
      }
    }
  }
}

// ---------------- final normalize: out /= max(gate_sum, 1e-9) ----------------
__global__ __launch_bounds__(256) void norm_kernel(float* __restrict__ out,
                                                   const float* __restrict__ gs) {
  int i = blockIdx.x * blockDim.x + threadIdx.x;
  const int n4 = T_TOK * H_DIM / 4;
  const int stride = gridDim.x * blockDim.x;
  for (; i < n4; i += stride) {
    const int t = i / (H_DIM / 4);
    const float inv = 1.0f / fmaxf(gs[t], 1e-9f);
    float4 v = reinterpret_cast<float4*>(out)[i];
    v.x *= inv; v.y *= inv; v.z *= inv; v.w *= inv;
    reinterpret_cast<float4*>(out)[i] = v;
  }
}

extern "C" void kernel_launch(void* const* d_in, const int* in_sizes, int n_in,
                              void* d_out, int out_size, void* d_ws, size_t ws_size,
                              hipStream_t stream) {
  const float* x = (const float*)d_in[0];
  const float* nw = (const float*)d_in[1];
  const float* rw = (const float*)d_in[2];
  const float* rb = (const float*)d_in[3];
  const float* fc1w = (const float*)d_in[4];
  const float* fc1b = (const float*)d_in[5];
  const float* fc2w = (const float*)d_in[6];
  const float* fc2b = (const float*)d_in[7];
  float* out = (float*)d_out;

  char* ws = (char*)d_ws;
  size_t off = 0;
  auto alloc = [&](size_t b) {
    char* p = ws + off;
    off += (b + 255) & ~(size_t)255;
    return p;
  };
  __hip_bfloat16* xn = (__hip_bfloat16*)alloc((size_t)T_TOK * H_DIM * 2);
  u64* keys = (u64*)alloc((size_t)NE * T_TOK * 8);
  int* idxl = (int*)alloc((size_t)NE * CAP * 4);
  float* gatel = (float*)alloc((size_t)NE * CAP * 4);
  float* gsum = (float*)alloc((size_t)T_TOK * 4);

  // pick expert-chunk size that fits ws
  int EC = NE;
  while (EC > 1) {
    const size_t per = (size_t)EC * ((size_t)FF_DIM * H_DIM * 2 * 2 + (size_t)CAP * FF_DIM * 2);
    if (off + per + 4096 <= ws_size) break;
    EC >>= 1;
  }
  __hip_bfloat16* w1b = (__hip_bfloat16*)alloc((size_t)EC * FF_DIM * H_DIM * 2);
  __hip_bfloat16* w2b = (__hip_bfloat16*)alloc((size_t)EC * H_DIM * FF_DIM * 2);
  __hip_bfloat16* hmid = (__hip_bfloat16*)alloc((size_t)EC * CAP * FF_DIM * 2);

  hipMemsetAsync(d_out, 0, (size_t)T_TOK * H_DIM * 4, stream);
  hipMemsetAsync(gsum, 0, (size_t)T_TOK * 4, stream);

  router_kernel<<<T_TOK, 256, 0, stream>>>(x, nw, rw, rb, xn, keys);
  topk_kernel<<<NE, 256, 0, stream>>>(keys, idxl, gatel, gsum);

  for (int eb = 0; eb < NE; eb += EC) {
    const int n4 = EC * FF_DIM * H_DIM / 4;
    cvt_kernel<<<2048, 256, 0, stream>>>(fc1w + (size_t)eb * FF_DIM * H_DIM, w1b, n4);
    cvt_kernel<<<2048, 256, 0, stream>>>(fc2w + (size_t)eb * H_DIM * FF_DIM, w2b, n4);
    dim3 g1(FF_DIM / BN, CAP / BM, EC);
    gemm_kernel<0><<<g1, 256, 0, stream>>>(xn, w1b, fc1b, idxl, gatel, hmid, out, eb);
    dim3 g2(H_DIM / BN, CAP / BM, EC);
    gemm_kernel<1><<<g2, 256, 0, stream>>>(hmid, w2b, fc2b, idxl, gatel, hmid, out, eb);
  }
  norm_kernel<<<2048, 256, 0, stream>>>(out, gsum);
}

// Round 2
// 675.941 us; speedup vs baseline: 1.1881x; 1.1881x over previous
//
#include <hip/hip_runtime.h>
#include <hip/hip_bf16.h>

#define T_TOK 16384
#define H_DIM 1024
#define FF_DIM 4096
#define NE 8
#define CAP 2048
#define EPS_F 1e-5f

#define BM2 256
#define BN2 256
#define BK2 32

typedef __attribute__((ext_vector_type(4))) float f32x4;
typedef __attribute__((ext_vector_type(8))) short bf16x8;
typedef unsigned long long u64;
typedef unsigned int u32;

__device__ inline void gload_lds16(const void* g, void* l) {
  __builtin_amdgcn_global_load_lds(
      (const __attribute__((address_space(1))) unsigned int*)g,
      (__attribute__((address_space(3))) unsigned int*)l, 16, 0, 0);
}

__device__ inline unsigned short bf16_bits(float f) {
  __hip_bfloat16 h = __float2bfloat16(f);
  unsigned short u;
  __builtin_memcpy(&u, &h, 2);
  return u;
}

// ---------------- router: RMSNorm + logits + softmax + composite keys ----------------
__global__ __launch_bounds__(256) void router_kernel(
    const float* __restrict__ x, const float* __restrict__ nw,
    const float* __restrict__ rw, const float* __restrict__ rb,
    __hip_bfloat16* __restrict__ xn, u64* __restrict__ keys) {
  const int t = blockIdx.x;
  const int tid = threadIdx.x;
  const float4 v = reinterpret_cast<const float4*>(x + (size_t)t * H_DIM)[tid];
  float ss = v.x * v.x + v.y * v.y + v.z * v.z + v.w * v.w;
#pragma unroll
  for (int o = 32; o > 0; o >>= 1) ss += __shfl_down(ss, o);
  __shared__ float red[4];
  __shared__ float redl[4][NE];
  const int wv = tid >> 6, ln = tid & 63;
  if (ln == 0) red[wv] = ss;
  __syncthreads();
  const float tot = red[0] + red[1] + red[2] + red[3];
  const float scale = rsqrtf(tot * (1.0f / H_DIM) + EPS_F);
  const float4 w4 = reinterpret_cast<const float4*>(nw)[tid];
  float xv0 = v.x * scale * w4.x, xv1 = v.y * scale * w4.y;
  float xv2 = v.z * scale * w4.z, xv3 = v.w * scale * w4.w;
  ushort4 u4;
  u4.x = bf16_bits(xv0); u4.y = bf16_bits(xv1);
  u4.z = bf16_bits(xv2); u4.w = bf16_bits(xv3);
  reinterpret_cast<ushort4*>(xn + (size_t)t * H_DIM)[tid] = u4;
  float lg[NE];
#pragma unroll
  for (int e = 0; e < NE; ++e) {
    const float4 r4 = reinterpret_cast<const float4*>(rw + (size_t)e * H_DIM)[tid];
    lg[e] = xv0 * r4.x + xv1 * r4.y + xv2 * r4.z + xv3 * r4.w;
  }
#pragma unroll
  for (int o = 32; o > 0; o >>= 1) {
#pragma unroll
    for (int e = 0; e < NE; ++e) lg[e] += __shfl_down(lg[e], o);
  }
  if (ln == 0) {
#pragma unroll
    for (int e = 0; e < NE; ++e) redl[wv][e] = lg[e];
  }
  __syncthreads();
  if (tid == 0) {
    float l[NE];
    float m = -1e30f;
#pragma unroll
    for (int e = 0; e < NE; ++e) {
      l[e] = redl[0][e] + redl[1][e] + redl[2][e] + redl[3][e] + rb[e];
      m = fmaxf(m, l[e]);
    }
    float s = 0.f;
#pragma unroll
    for (int e = 0; e < NE; ++e) { l[e] = expf(l[e] - m); s += l[e]; }
    const float inv = 1.0f / s;
#pragma unroll
    for (int e = 0; e < NE; ++e) {
      const float p = l[e] * inv;
      const u64 key = ((u64)__float_as_uint(p) << 32) | (u32)(0xFFFFFFFFu - (u32)t);
      keys[(size_t)e * T_TOK + t] = key;
    }
  }
}

// ---------------- per-expert radix select (exact, distinct 64-bit keys) ----------------
__global__ __launch_bounds__(256) void topk_kernel(
    const u64* __restrict__ keys, int* __restrict__ idxl,
    float* __restrict__ gatel, float* __restrict__ gsum) {
  const int e = blockIdx.x;
  const int tid = threadIdx.x;
  const u64* ke = keys + (size_t)e * T_TOK;
  __shared__ int hist[256];
  __shared__ u64 s_pref;
  __shared__ int s_k;
  __shared__ int s_cnt;
  u64 pref = 0;
  int pbits = 0;
  int kneed = CAP;
  for (int pass = 0; pass < 8; ++pass) {
    hist[tid] = 0;
    __syncthreads();
    const int shift = 56 - 8 * pass;
    for (int i = tid; i < T_TOK; i += 256) {
      const u64 key = ke[i];
      const bool ok = (pbits == 0) || ((key >> (64 - pbits)) == pref);
      if (ok) atomicAdd(&hist[(int)((key >> shift) & 255)], 1);
    }
    __syncthreads();
    if (tid == 0) {
      int cum = 0;
      int d = 255;
      for (; d >= 0; --d) {
        cum += hist[d];
        if (cum >= kneed) break;
      }
      s_k = kneed - (cum - hist[d]);
      s_pref = (pref << 8) | (u64)(u32)d;
    }
    __syncthreads();
    pref = s_pref;
    kneed = s_k;
    pbits += 8;
    __syncthreads();
  }
  if (tid == 0) s_cnt = 0;
  __syncthreads();
  for (int i = tid; i < T_TOK; i += 256) {
    const u64 key = ke[i];
    if (key >= pref) {
      const int pos = atomicAdd(&s_cnt, 1);
      if (pos < CAP) {
        const int tok = (int)(0xFFFFFFFFu - (u32)(key & 0xFFFFFFFFu));
        const float p = __uint_as_float((u32)(key >> 32));
        idxl[e * CAP + pos] = tok;
        gatel[e * CAP + pos] = p;
        atomicAdd(gsum + tok, p);
      }
    }
  }
}

// ---------------- fp32 -> bf16 weight conversion ----------------
__global__ __launch_bounds__(256) void cvt_kernel(const float* __restrict__ src,
                                                  __hip_bfloat16* __restrict__ dst, int n4) {
  int i = blockIdx.x * blockDim.x + threadIdx.x;
  const int stride = gridDim.x * blockDim.x;
  for (; i < n4; i += stride) {
    const float4 v = reinterpret_cast<const float4*>(src)[i];
    ushort4 o;
    o.x = bf16_bits(v.x); o.y = bf16_bits(v.y);
    o.z = bf16_bits(v.z); o.w = bf16_bits(v.w);
    reinterpret_cast<ushort4*>(dst)[i] = o;
  }
}

// ---------------- MFMA GEMM, 256x256 tile, 2-phase double-buffered pipeline ----------------
// MODE 0: fc1  C[cap,FF] = gather(xn, idx) @ w1^T  -> bias+gelu(tanh) -> hmid (bf16)
// MODE 1: fc2  C[cap,H]  = hmid @ w2^T             -> bias, atomic gated scatter to out
template <int MODE>
__global__ __launch_bounds__(512, 2) void gemm2_kernel(
    const __hip_bfloat16* __restrict__ Asrc, const __hip_bfloat16* __restrict__ Bw,
    const float* __restrict__ bias, const int* __restrict__ idxl,
    const float* __restrict__ gatel, __hip_bfloat16* __restrict__ hmid,
    float* __restrict__ out, int ebase) {
  constexpr int N = (MODE == 0) ? FF_DIM : H_DIM;
  constexpr int K = (MODE == 0) ? H_DIM : FF_DIM;
  constexpr int NBN = N / BN2;                  // 16 or 4
  constexpr int LOG_NBN = (MODE == 0) ? 4 : 2;
  constexpr int BPE = (CAP / BM2) * NBN;        // 128 or 32
  constexpr int LOG_BPE = (MODE == 0) ? 7 : 5;
  constexpr int NT = K / BK2;

  // T1: bijective XCD swizzle (nwg always divisible by 8 here)
  const int nwg = gridDim.x;
  const int wg0 = blockIdx.x;
  const int wg = (wg0 & 7) * (nwg >> 3) + (wg0 >> 3);
  const int z = wg >> LOG_BPE;
  const int rr = wg & (BPE - 1);
  const int bm = rr >> LOG_NBN;
  const int bn = rr & (NBN - 1);
  const int e = ebase + z;

  const int tid = threadIdx.x;
  const int lane = tid & 63;
  const int w = tid >> 6;
  const int wr = w >> 2, wc = w & 3;      // 2 x 4 wave grid; wave owns 128x64
  const int fr = lane & 15, q = lane >> 4;

  __shared__ char smem[65536];  // A0@0 B0@16K A1@32K B1@48K (each 256x32 bf16 = 16KB)

  // --- staging: thread covers rows {srow, srow+128}, 16B granule sg, XOR-swizzled source
  const int srow = tid >> 2;
  const int sg = tid & 3;
  const int skoff = (sg ^ ((srow >> 1) & 3)) * 8;  // element offset within BK slice

  const __hip_bfloat16* asrc0;
  const __hip_bfloat16* asrc1;
  if constexpr (MODE == 0) {
    const int t0 = idxl[e * CAP + bm * BM2 + srow];
    const int t1 = idxl[e * CAP + bm * BM2 + 128 + srow];
    asrc0 = Asrc + (size_t)t0 * H_DIM + skoff;
    asrc1 = Asrc + (size_t)t1 * H_DIM + skoff;
  } else {
    asrc0 = Asrc + ((size_t)z * CAP + bm * BM2 + srow) * FF_DIM + skoff;
    asrc1 = asrc0 + (size_t)128 * FF_DIM;
  }
  const __hip_bfloat16* bsrc0 = Bw + (size_t)z * N * K + (size_t)(bn * BN2 + srow) * K + skoff;
  const __hip_bfloat16* bsrc1 = bsrc0 + (size_t)128 * K;

  // --- fragment read offsets (same XOR on read side)
  const int slot = ((q ^ ((fr >> 1) & 3)) << 4);
  int offA[8], offB[4];
#pragma unroll
  for (int m = 0; m < 8; ++m) offA[m] = (wr * 128 + m * 16 + fr) * 64 + slot;
#pragma unroll
  for (int n = 0; n < 4; ++n) offB[n] = 16384 + (wc * 64 + n * 16 + fr) * 64 + slot;

  f32x4 acc[8][4] = {};

#define STAGE(buf, kt)                                              \
  do {                                                              \
    const int k0_ = (kt)*BK2;                                       \
    char* da_ = smem + (buf)*32768 + tid * 16;                      \
    gload_lds16(asrc0 + k0_, da_);                                  \
    gload_lds16(asrc1 + k0_, da_ + 8192);                           \
    gload_lds16(bsrc0 + k0_, da_ + 16384);                          \
    gload_lds16(bsrc1 + k0_, da_ + 24576);                          \
  } while (0)

  STAGE(0, 0);
  asm volatile("s_waitcnt vmcnt(0)");
  __builtin_amdgcn_s_barrier();
  __builtin_amdgcn_sched_barrier(0);

  for (int kt = 0; kt < NT; ++kt) {
    const int cur = kt & 1;
    if (kt + 1 < NT) STAGE(cur ^ 1, kt + 1);  // issue next tile early (hides under MFMA)
    const char* base = smem + cur * 32768;
    bf16x8 af[8], bfr[4];
#pragma unroll
    for (int m = 0; m < 8; ++m) af[m] = *reinterpret_cast<const bf16x8*>(base + offA[m]);
#pragma unroll
    for (int n = 0; n < 4; ++n) bfr[n] = *reinterpret_cast<const bf16x8*>(base + offB[n]);
    asm volatile("s_waitcnt lgkmcnt(0)");
    __builtin_amdgcn_sched_barrier(0);
    __builtin_amdgcn_s_setprio(1);
#pragma unroll
    for (int m = 0; m < 8; ++m) {
#pragma unroll
      for (int n = 0; n < 4; ++n)
        acc[m][n] = __builtin_amdgcn_mfma_f32_16x16x32_bf16(af[m], bfr[n], acc[m][n], 0, 0, 0);
    }
    __builtin_amdgcn_s_setprio(0);
    if (kt + 1 < NT) {
      asm volatile("s_waitcnt vmcnt(0)");
      __builtin_amdgcn_s_barrier();
      __builtin_amdgcn_sched_barrier(0);
    }
  }
#undef STAGE

  if constexpr (MODE == 0) {
#pragma unroll
    for (int m = 0; m < 8; ++m) {
      const int rbase = bm * BM2 + wr * 128 + m * 16 + q * 4;
#pragma unroll
      for (int n = 0; n < 4; ++n) {
        const int gn = bn * BN2 + wc * 64 + n * 16 + fr;
        const float bb = bias[e * FF_DIM + gn];
#pragma unroll
        for (int i = 0; i < 4; ++i) {
          const float v = acc[m][n][i] + bb;
          const float u = v * (1.5957691216f + 0.0713548162972f * v * v);
          const float s = 1.0f / (1.0f + __expf(-u));
          hmid[((size_t)z * CAP + rbase + i) * FF_DIM + gn] = __float2bfloat16(v * s);
        }
      }
    }
  } else {
#pragma unroll
    for (int m = 0; m < 8; ++m) {
      const int rbase = bm * BM2 + wr * 128 + m * 16 + q * 4;
      int tok[4];
      float gt[4];
#pragma unroll
      for (int i = 0; i < 4; ++i) {
        tok[i] = idxl[e * CAP + rbase + i];
        gt[i] = gatel[e * CAP + rbase + i];
      }
#pragma unroll
      for (int n = 0; n < 4; ++n) {
        const int gn = bn * BN2 + wc * 64 + n * 16 + fr;
        const float bb = bias[e * H_DIM + gn];
#pragma unroll
        for (int i = 0; i < 4; ++i) {
          const float vv = (acc[m][n][i] + bb) * gt[i];
          atomicAdd(out + (size_t)tok[i] * H_DIM + gn, vv);
        }
      }
    }
  }
}

// ---------------- final normalize: out /= max(gate_sum, 1e-9) ----------------
__global__ __launch_bounds__(256) void norm_kernel(float* __restrict__ out,
                                                   const float* __restrict__ gs) {
  int i = blockIdx.x * blockDim.x + threadIdx.x;
  const int n4 = T_TOK * H_DIM / 4;
  const int stride = gridDim.x * blockDim.x;
  for (; i < n4; i += stride) {
    const int t = i / (H_DIM / 4);
    const float inv = 1.0f / fmaxf(gs[t], 1e-9f);
    float4 v = reinterpret_cast<float4*>(out)[i];
    v.x *= inv; v.y *= inv; v.z *= inv; v.w *= inv;
    reinterpret_cast<float4*>(out)[i] = v;
  }
}

extern "C" void kernel_launch(void* const* d_in, const int* in_sizes, int n_in,
                              void* d_out, int out_size, void* d_ws, size_t ws_size,
                              hipStream_t stream) {
  const float* x = (const float*)d_in[0];
  const float* nw = (const float*)d_in[1];
  const float* rw = (const float*)d_in[2];
  const float* rb = (const float*)d_in[3];
  const float* fc1w = (const float*)d_in[4];
  const float* fc1b = (const float*)d_in[5];
  const float* fc2w = (const float*)d_in[6];
  const float* fc2b = (const float*)d_in[7];
  float* out = (float*)d_out;

  char* ws = (char*)d_ws;
  size_t off = 0;
  auto alloc = [&](size_t b) {
    char* p = ws + off;
    off += (b + 255) & ~(size_t)255;
    return p;
  };
  __hip_bfloat16* xn = (__hip_bfloat16*)alloc((size_t)T_TOK * H_DIM * 2);
  u64* keys = (u64*)alloc((size_t)NE * T_TOK * 8);
  int* idxl = (int*)alloc((size_t)NE * CAP * 4);
  float* gatel = (float*)alloc((size_t)NE * CAP * 4);
  float* gsum = (float*)alloc((size_t)T_TOK * 4);

  // pick expert-chunk size that fits ws
  int EC = NE;
  while (EC > 1) {
    const size_t per = (size_t)EC * ((size_t)FF_DIM * H_DIM * 2 * 2 + (size_t)CAP * FF_DIM * 2);
    if (off + per + 4096 <= ws_size) break;
    EC >>= 1;
  }
  __hip_bfloat16* w1b = (__hip_bfloat16*)alloc((size_t)EC * FF_DIM * H_DIM * 2);
  __hip_bfloat16* w2b = (__hip_bfloat16*)alloc((size_t)EC * H_DIM * FF_DIM * 2);
  __hip_bfloat16* hmid = (__hip_bfloat16*)alloc((size_t)EC * CAP * FF_DIM * 2);

  hipMemsetAsync(d_out, 0, (size_t)T_TOK * H_DIM * 4, stream);
  hipMemsetAsync(gsum, 0, (size_t)T_TOK * 4, stream);

  router_kernel<<<T_TOK, 256, 0, stream>>>(x, nw, rw, rb, xn, keys);
  topk_kernel<<<NE, 256, 0, stream>>>(keys, idxl, gatel, gsum);

  for (int eb = 0; eb < NE; eb += EC) {
    const int n4 = EC * FF_DIM * H_DIM / 4;
    cvt_kernel<<<2048, 256, 0, stream>>>(fc1w + (size_t)eb * FF_DIM * H_DIM, w1b, n4);
    cvt_kernel<<<2048, 256, 0, stream>>>(fc2w + (size_t)eb * H_DIM * FF_DIM, w2b, n4);
    const int nb1 = EC * (CAP / BM2) * (FF_DIM / BN2);
    gemm2_kernel<0><<<nb1, 512, 0, stream>>>(xn, w1b, fc1b, idxl, gatel, hmid, out, eb);
    const int nb2 = EC * (CAP / BM2) * (H_DIM / BN2);
    gemm2_kernel<1><<<nb2, 512, 0, stream>>>(hmid, w2b, fc2b, idxl, gatel, hmid, out, eb);
  }
  norm_kernel<<<2048, 256, 0, stream>>>(out, gsum);
}

// Round 3
// 556.931 us; speedup vs baseline: 1.4420x; 1.2137x over previous
//
#include <hip/hip_runtime.h>
#include <hip/hip_bf16.h>

#define T_TOK 16384
#define H_DIM 1024
#define FF_DIM 4096
#define NE 8
#define CAP 2048
#define EPS_F 1e-5f

#define BM2 256
#define BN2 256
#define BK2 32

typedef __attribute__((ext_vector_type(4))) float f32x4;
typedef __attribute__((ext_vector_type(8))) short bf16x8;
typedef unsigned long long u64;
typedef unsigned int u32;

__device__ inline void gload_lds16(const void* g, void* l) {
  __builtin_amdgcn_global_load_lds(
      (const __attribute__((address_space(1))) unsigned int*)g,
      (__attribute__((address_space(3))) unsigned int*)l, 16, 0, 0);
}

__device__ inline unsigned short bf16_bits(float f) {
  __hip_bfloat16 h = __float2bfloat16(f);
  unsigned short u;
  __builtin_memcpy(&u, &h, 2);
  return u;
}

__device__ inline float bits_f32(unsigned short u) {
  const u32 x = ((u32)u) << 16;
  float f;
  __builtin_memcpy(&f, &x, 4);
  return f;
}

// ---------------- router: RMSNorm + logits + softmax + composite keys ----------------
__global__ __launch_bounds__(256) void router_kernel(
    const float* __restrict__ x, const float* __restrict__ nw,
    const float* __restrict__ rw, const float* __restrict__ rb,
    __hip_bfloat16* __restrict__ xn, u64* __restrict__ keys) {
  const int t = blockIdx.x;
  const int tid = threadIdx.x;
  const float4 v = reinterpret_cast<const float4*>(x + (size_t)t * H_DIM)[tid];
  float ss = v.x * v.x + v.y * v.y + v.z * v.z + v.w * v.w;
#pragma unroll
  for (int o = 32; o > 0; o >>= 1) ss += __shfl_down(ss, o);
  __shared__ float red[4];
  __shared__ float redl[4][NE];
  const int wv = tid >> 6, ln = tid & 63;
  if (ln == 0) red[wv] = ss;
  __syncthreads();
  const float tot = red[0] + red[1] + red[2] + red[3];
  const float scale = rsqrtf(tot * (1.0f / H_DIM) + EPS_F);
  const float4 w4 = reinterpret_cast<const float4*>(nw)[tid];
  float xv0 = v.x * scale * w4.x, xv1 = v.y * scale * w4.y;
  float xv2 = v.z * scale * w4.z, xv3 = v.w * scale * w4.w;
  ushort4 u4;
  u4.x = bf16_bits(xv0); u4.y = bf16_bits(xv1);
  u4.z = bf16_bits(xv2); u4.w = bf16_bits(xv3);
  reinterpret_cast<ushort4*>(xn + (size_t)t * H_DIM)[tid] = u4;
  float lg[NE];
#pragma unroll
  for (int e = 0; e < NE; ++e) {
    const float4 r4 = reinterpret_cast<const float4*>(rw + (size_t)e * H_DIM)[tid];
    lg[e] = xv0 * r4.x + xv1 * r4.y + xv2 * r4.z + xv3 * r4.w;
  }
#pragma unroll
  for (int o = 32; o > 0; o >>= 1) {
#pragma unroll
    for (int e = 0; e < NE; ++e) lg[e] += __shfl_down(lg[e], o);
  }
  if (ln == 0) {
#pragma unroll
    for (int e = 0; e < NE; ++e) redl[wv][e] = lg[e];
  }
  __syncthreads();
  if (tid == 0) {
    float l[NE];
    float m = -1e30f;
#pragma unroll
    for (int e = 0; e < NE; ++e) {
      l[e] = redl[0][e] + redl[1][e] + redl[2][e] + redl[3][e] + rb[e];
      m = fmaxf(m, l[e]);
    }
    float s = 0.f;
#pragma unroll
    for (int e = 0; e < NE; ++e) { l[e] = expf(l[e] - m); s += l[e]; }
    const float inv = 1.0f / s;
#pragma unroll
    for (int e = 0; e < NE; ++e) {
      const float p = l[e] * inv;
      const u64 key = ((u64)__float_as_uint(p) << 32) | (u32)(0xFFFFFFFFu - (u32)t);
      keys[(size_t)e * T_TOK + t] = key;
    }
  }
}

// ---------------- per-expert radix select + inverse token map ----------------
__global__ __launch_bounds__(1024) void topk_kernel(
    const u64* __restrict__ keys, int* __restrict__ idxl,
    float* __restrict__ gatel, int* __restrict__ tok_list, int* __restrict__ tok_cnt) {
  const int e = blockIdx.x;
  const int tid = threadIdx.x;
  const int lane = tid & 63;
  const u64* ke = keys + (size_t)e * T_TOK;
  __shared__ int hist[256];
  __shared__ u64 s_pref;
  __shared__ int s_k;
  __shared__ int s_cnt;
  u64 pref = 0;
  int pbits = 0;
  int kneed = CAP;
  for (int pass = 0; pass < 8; ++pass) {
    if (tid < 256) hist[tid] = 0;
    __syncthreads();
    const int shift = 56 - 8 * pass;
    for (int i = tid; i < T_TOK; i += 1024) {
      const u64 key = ke[i];
      const bool ok = (pbits == 0) || ((key >> (64 - pbits)) == pref);
      const int d = ok ? (int)((key >> shift) & 255) : -1;
      // wave-aggregated histogram update (handles clustered digits)
      u64 act = __ballot(ok);
      while (act) {
        const int src = __ffsll((long long)act) - 1;
        const int dl = __shfl(d, src);
        const u64 mb = __ballot(ok && (d == dl));
        if (lane == src) atomicAdd(&hist[dl], (int)__popcll(mb));
        act &= ~mb;
      }
    }
    __syncthreads();
    if (tid == 0) {
      int cum = 0;
      int d = 255;
      for (; d >= 0; --d) {
        cum += hist[d];
        if (cum >= kneed) break;
      }
      s_k = kneed - (cum - hist[d]);
      s_pref = (pref << 8) | (u64)(u32)d;
    }
    __syncthreads();
    pref = s_pref;
    kneed = s_k;
    pbits += 8;
    __syncthreads();
  }
  if (tid == 0) s_cnt = 0;
  __syncthreads();
  for (int i = tid; i < T_TOK; i += 1024) {
    const u64 key = ke[i];
    if (key >= pref) {
      const int pos = atomicAdd(&s_cnt, 1);
      if (pos < CAP) {
        const int tok = (int)(0xFFFFFFFFu - (u32)(key & 0xFFFFFFFFu));
        const float p = __uint_as_float((u32)(key >> 32));
        idxl[e * CAP + pos] = tok;
        gatel[e * CAP + pos] = p;
        const int j = atomicAdd(tok_cnt + tok, 1);
        if (j < NE) tok_list[tok * NE + j] = e * CAP + pos;
      }
    }
  }
}

// ---------------- fp32 -> bf16 weight conversion ----------------
__global__ __launch_bounds__(256) void cvt_kernel(const float* __restrict__ src,
                                                  __hip_bfloat16* __restrict__ dst, int n4) {
  int i = blockIdx.x * blockDim.x + threadIdx.x;
  const int stride = gridDim.x * blockDim.x;
  for (; i < n4; i += stride) {
    const float4 v = reinterpret_cast<const float4*>(src)[i];
    ushort4 o;
    o.x = bf16_bits(v.x); o.y = bf16_bits(v.y);
    o.z = bf16_bits(v.z); o.w = bf16_bits(v.w);
    reinterpret_cast<ushort4*>(dst)[i] = o;
  }
}

// ---------------- MFMA GEMM, 256x256 tile, depth-3 counted-vmcnt pipeline ----------------
// MODE 0: fc1  C = gather(xn, idx) @ w1^T -> bias+gelu -> hmid (bf16)
// MODE 1: fc2  C = hmid @ w2^T            -> bias, gate-weighted bf16 store to ye
template <int MODE>
__global__ __launch_bounds__(512, 2) void gemm3_kernel(
    const __hip_bfloat16* __restrict__ Asrc, const __hip_bfloat16* __restrict__ Bw,
    const float* __restrict__ bias, const int* __restrict__ idxl,
    const float* __restrict__ gatel, __hip_bfloat16* __restrict__ hmid,
    __hip_bfloat16* __restrict__ ye, int ebase) {
  constexpr int N = (MODE == 0) ? FF_DIM : H_DIM;
  constexpr int K = (MODE == 0) ? H_DIM : FF_DIM;
  constexpr int NBN = N / BN2;
  constexpr int LOG_NBN = (MODE == 0) ? 4 : 2;
  constexpr int BPE = (CAP / BM2) * NBN;
  constexpr int LOG_BPE = (MODE == 0) ? 7 : 5;
  constexpr int NT = K / BK2;

  const int nwg = gridDim.x;
  const int wg0 = blockIdx.x;
  const int wg = (wg0 & 7) * (nwg >> 3) + (wg0 >> 3);
  const int z = wg >> LOG_BPE;
  const int rr = wg & (BPE - 1);
  const int bm = rr >> LOG_NBN;
  const int bn = rr & (NBN - 1);
  const int e = ebase + z;

  const int tid = threadIdx.x;
  const int lane = tid & 63;
  const int w = tid >> 6;
  const int wr = w >> 2, wc = w & 3;  // 2x4 wave grid; wave owns 128x64
  const int fr = lane & 15, q = lane >> 4;

  __shared__ char smem[131072];  // 4 buffers x 32KB (A 16K + B 16K each)

  const int srow = tid >> 2;
  const int sg = tid & 3;
  const int skoff = (sg ^ ((srow >> 1) & 3)) * 8;

  const __hip_bfloat16* asrc0;
  const __hip_bfloat16* asrc1;
  if constexpr (MODE == 0) {
    const int t0 = idxl[e * CAP + bm * BM2 + srow];
    const int t1 = idxl[e * CAP + bm * BM2 + 128 + srow];
    asrc0 = Asrc + (size_t)t0 * H_DIM + skoff;
    asrc1 = Asrc + (size_t)t1 * H_DIM + skoff;
  } else {
    asrc0 = Asrc + ((size_t)z * CAP + bm * BM2 + srow) * FF_DIM + skoff;
    asrc1 = asrc0 + (size_t)128 * FF_DIM;
  }
  const __hip_bfloat16* bsrc0 = Bw + (size_t)z * N * K + (size_t)(bn * BN2 + srow) * K + skoff;
  const __hip_bfloat16* bsrc1 = bsrc0 + (size_t)128 * K;

  const int slot = ((q ^ ((fr >> 1) & 3)) << 4);
  int offA[8], offB[4];
#pragma unroll
  for (int m = 0; m < 8; ++m) offA[m] = (wr * 128 + m * 16 + fr) * 64 + slot;
#pragma unroll
  for (int n = 0; n < 4; ++n) offB[n] = 16384 + (wc * 64 + n * 16 + fr) * 64 + slot;

  f32x4 acc[8][4] = {};

#define STAGE4(buf, kt)                                     \
  do {                                                      \
    const int k0_ = (kt)*BK2;                               \
    char* d_ = smem + (buf)*32768 + tid * 16;               \
    gload_lds16(asrc0 + k0_, d_);                           \
    gload_lds16(asrc1 + k0_, d_ + 8192);                    \
    gload_lds16(bsrc0 + k0_, d_ + 16384);                   \
    gload_lds16(bsrc1 + k0_, d_ + 24576);                   \
  } while (0)

  STAGE4(0, 0);
  STAGE4(1, 1);
  STAGE4(2, 2);
  __builtin_amdgcn_sched_barrier(0);

  for (int kt = 0; kt < NT; ++kt) {
    const int cur = kt & 3;
    const int pf = (kt + 3 < NT) ? (kt + 3) : (kt + 3 - NT);  // wrapped prefetch tile
    const int k0p = pf * BK2;
    char* pdst = smem + ((kt + 3) & 3) * 32768 + tid * 16;

    asm volatile("s_waitcnt vmcnt(8)");  // oldest stage (tile kt) complete; 8 newer in flight
    __builtin_amdgcn_s_barrier();
    __builtin_amdgcn_sched_barrier(0);
    const char* base = smem + cur * 32768;
    bf16x8 af[8], bfr[4];
#pragma unroll
    for (int n = 0; n < 4; ++n) bfr[n] = *reinterpret_cast<const bf16x8*>(base + offB[n]);
    af[0] = *reinterpret_cast<const bf16x8*>(base + offA[0]);
    af[1] = *reinterpret_cast<const bf16x8*>(base + offA[1]);
    af[2] = *reinterpret_cast<const bf16x8*>(base + offA[2]);
    af[3] = *reinterpret_cast<const bf16x8*>(base + offA[3]);
    __builtin_amdgcn_sched_barrier(0);
    // ---- phase 0
    af[4] = *reinterpret_cast<const bf16x8*>(base + offA[4]);
    af[5] = *reinterpret_cast<const bf16x8*>(base + offA[5]);
    gload_lds16(asrc0 + k0p, pdst);
    asm volatile("s_waitcnt lgkmcnt(4)");
    __builtin_amdgcn_sched_barrier(0);
    __builtin_amdgcn_s_setprio(1);
#pragma unroll
    for (int m = 0; m < 2; ++m)
#pragma unroll
      for (int n = 0; n < 4; ++n)
        acc[m][n] = __builtin_amdgcn_mfma_f32_16x16x32_bf16(af[m], bfr[n], acc[m][n], 0, 0, 0);
    __builtin_amdgcn_s_setprio(0);
    __builtin_amdgcn_sched_barrier(0);
    // ---- phase 1
    af[6] = *reinterpret_cast<const bf16x8*>(base + offA[6]);
    af[7] = *reinterpret_cast<const bf16x8*>(base + offA[7]);
    gload_lds16(asrc1 + k0p, pdst + 8192);
    asm volatile("s_waitcnt lgkmcnt(4)");
    __builtin_amdgcn_sched_barrier(0);
    __builtin_amdgcn_s_setprio(1);
#pragma unroll
    for (int m = 2; m < 4; ++m)
#pragma unroll
      for (int n = 0; n < 4; ++n)
        acc[m][n] = __builtin_amdgcn_mfma_f32_16x16x32_bf16(af[m], bfr[n], acc[m][n], 0, 0, 0);
    __builtin_amdgcn_s_setprio(0);
    __builtin_amdgcn_sched_barrier(0);
    // ---- phase 2
    gload_lds16(bsrc0 + k0p, pdst + 16384);
    asm volatile("s_waitcnt lgkmcnt(2)");
    __builtin_amdgcn_sched_barrier(0);
    __builtin_amdgcn_s_setprio(1);
#pragma unroll
    for (int m = 4; m < 6; ++m)
#pragma unroll
      for (int n = 0; n < 4; ++n)
        acc[m][n] = __builtin_amdgcn_mfma_f32_16x16x32_bf16(af[m], bfr[n], acc[m][n], 0, 0, 0);
    __builtin_amdgcn_s_setprio(0);
    __builtin_amdgcn_sched_barrier(0);
    // ---- phase 3
    gload_lds16(bsrc1 + k0p, pdst + 24576);
    asm volatile("s_waitcnt lgkmcnt(0)");
    __builtin_amdgcn_sched_barrier(0);
    __builtin_amdgcn_s_setprio(1);
#pragma unroll
    for (int m = 6; m < 8; ++m)
#pragma unroll
      for (int n = 0; n < 4; ++n)
        acc[m][n] = __builtin_amdgcn_mfma_f32_16x16x32_bf16(af[m], bfr[n], acc[m][n], 0, 0, 0);
    __builtin_amdgcn_s_setprio(0);
    __builtin_amdgcn_sched_barrier(0);
  }
#undef STAGE4

  if constexpr (MODE == 0) {
#pragma unroll
    for (int m = 0; m < 8; ++m) {
      const int rbase = bm * BM2 + wr * 128 + m * 16 + q * 4;
#pragma unroll
      for (int n = 0; n < 4; ++n) {
        const int gn = bn * BN2 + wc * 64 + n * 16 + fr;
        const float bb = bias[e * FF_DIM + gn];
#pragma unroll
        for (int i = 0; i < 4; ++i) {
          const float v = acc[m][n][i] + bb;
          const float u = v * (1.5957691216f + 0.0713548162972f * v * v);
          const float s = 1.0f / (1.0f + __expf(-u));
          hmid[((size_t)z * CAP + rbase + i) * FF_DIM + gn] = __float2bfloat16(v * s);
        }
      }
    }
  } else {
#pragma unroll
    for (int m = 0; m < 8; ++m) {
      const int rbase = bm * BM2 + wr * 128 + m * 16 + q * 4;
      float gt[4];
#pragma unroll
      for (int i = 0; i < 4; ++i) gt[i] = gatel[e * CAP + rbase + i];
#pragma unroll
      for (int n = 0; n < 4; ++n) {
        const int gn = bn * BN2 + wc * 64 + n * 16 + fr;
        const float bb = bias[e * H_DIM + gn];
#pragma unroll
        for (int i = 0; i < 4; ++i)
          ye[((size_t)e * CAP + rbase + i) * H_DIM + gn] =
              __float2bfloat16((acc[m][n][i] + bb) * gt[i]);
      }
    }
  }
}

// ---------------- combine: gather <=8 expert rows per token, sum, normalize ----------------
__global__ __launch_bounds__(256) void combine_kernel(
    const __hip_bfloat16* __restrict__ ye, const float* __restrict__ gatel,
    const int* __restrict__ tok_list, const int* __restrict__ tok_cnt,
    float* __restrict__ out) {
  const int t = blockIdx.x;
  const int tid = threadIdx.x;
  const int cnt = tok_cnt[t];
  float a0 = 0.f, a1 = 0.f, a2 = 0.f, a3 = 0.f, gs = 0.f;
  for (int j = 0; j < cnt && j < NE; ++j) {
    const int ent = tok_list[t * NE + j];
    gs += gatel[ent];
    const ushort4 v = reinterpret_cast<const ushort4*>(ye + (size_t)ent * H_DIM)[tid];
    a0 += bits_f32(v.x);
    a1 += bits_f32(v.y);
    a2 += bits_f32(v.z);
    a3 += bits_f32(v.w);
  }
  const float inv = 1.0f / fmaxf(gs, 1e-9f);
  float4 o;
  o.x = a0 * inv; o.y = a1 * inv; o.z = a2 * inv; o.w = a3 * inv;
  reinterpret_cast<float4*>(out + (size_t)t * H_DIM)[tid] = o;
}

extern "C" void kernel_launch(void* const* d_in, const int* in_sizes, int n_in,
                              void* d_out, int out_size, void* d_ws, size_t ws_size,
                              hipStream_t stream) {
  const float* x = (const float*)d_in[0];
  const float* nw = (const float*)d_in[1];
  const float* rw = (const float*)d_in[2];
  const float* rb = (const float*)d_in[3];
  const float* fc1w = (const float*)d_in[4];
  const float* fc1b = (const float*)d_in[5];
  const float* fc2w = (const float*)d_in[6];
  const float* fc2b = (const float*)d_in[7];
  float* out = (float*)d_out;

  char* ws = (char*)d_ws;
  size_t off = 0;
  auto alloc = [&](size_t b) {
    char* p = ws + off;
    off += (b + 255) & ~(size_t)255;
    return p;
  };
  __hip_bfloat16* xn = (__hip_bfloat16*)alloc((size_t)T_TOK * H_DIM * 2);
  u64* keys = (u64*)alloc((size_t)NE * T_TOK * 8);
  int* idxl = (int*)alloc((size_t)NE * CAP * 4);
  float* gatel = (float*)alloc((size_t)NE * CAP * 4);
  int* tok_list = (int*)alloc((size_t)T_TOK * NE * 4);
  int* tok_cnt = (int*)alloc((size_t)T_TOK * 4);
  __hip_bfloat16* ye = (__hip_bfloat16*)alloc((size_t)NE * CAP * H_DIM * 2);

  int EC = NE;
  while (EC > 1) {
    const size_t per = (size_t)EC * ((size_t)FF_DIM * H_DIM * 2 * 2 + (size_t)CAP * FF_DIM * 2);
    if (off + per + 4096 <= ws_size) break;
    EC >>= 1;
  }
  __hip_bfloat16* w1b = (__hip_bfloat16*)alloc((size_t)EC * FF_DIM * H_DIM * 2);
  __hip_bfloat16* w2b = (__hip_bfloat16*)alloc((size_t)EC * H_DIM * FF_DIM * 2);
  __hip_bfloat16* hmid = (__hip_bfloat16*)alloc((size_t)EC * CAP * FF_DIM * 2);

  hipMemsetAsync(tok_cnt, 0, (size_t)T_TOK * 4, stream);

  router_kernel<<<T_TOK, 256, 0, stream>>>(x, nw, rw, rb, xn, keys);
  topk_kernel<<<NE, 1024, 0, stream>>>(keys, idxl, gatel, tok_list, tok_cnt);

  for (int eb = 0; eb < NE; eb += EC) {
    const int n4 = EC * FF_DIM * H_DIM / 4;
    cvt_kernel<<<2048, 256, 0, stream>>>(fc1w + (size_t)eb * FF_DIM * H_DIM, w1b, n4);
    cvt_kernel<<<2048, 256, 0, stream>>>(fc2w + (size_t)eb * H_DIM * FF_DIM, w2b, n4);
    const int nb1 = EC * (CAP / BM2) * (FF_DIM / BN2);
    gemm3_kernel<0><<<nb1, 512, 0, stream>>>(xn, w1b, fc1b, idxl, gatel, hmid, ye, eb);
    const int nb2 = EC * (CAP / BM2) * (H_DIM / BN2);
    gemm3_kernel<1><<<nb2, 512, 0, stream>>>(hmid, w2b, fc2b, idxl, gatel, hmid, ye, eb);
  }
  combine_kernel<<<T_TOK, 256, 0, stream>>>(ye, gatel, tok_list, tok_cnt, out);
}